// Round 1
// baseline (680.007 us; speedup 1.0000x reference)
//
#include <hip/hip_runtime.h>
#include <stdint.h>

#define D 96
#define D3 (96*96*96)
#define IMW 640
#define IMH 480
#define HW (IMW*IMH)
#define NPTS 150000
#define VOXEL 0.04f
#define TRUNC 5.0f
#define RAYINC 1.5f
#define DEPTHMIN 0.025f
#define NSTEPS 67
#define EPSN 1e-5f

struct Scal {
  unsigned minD, maxD, minT, maxT, cntM, cntN;
  float sumD, sumN, lossD, lossN;
};

__global__ void k_fill(float* __restrict__ g, float* __restrict__ gt, Scal* sc) {
  int i = blockIdx.x * blockDim.x + threadIdx.x;
  if (i < D3) { g[i] = TRUNC; gt[i] = TRUNC; }
  if (i == 0) { sc->lossD = 0.f; sc->lossN = 0.f; }
}

__global__ void k_scatter(const int* __restrict__ coords, const float* __restrict__ sdf,
                          const float* __restrict__ sdft,
                          float* __restrict__ g, float* __restrict__ gt,
                          uint8_t* __restrict__ occ) {
  int i = blockIdx.x * blockDim.x + threadIdx.x;
  if (i >= NPTS) return;
  int l0 = coords[i*4+3], l1 = coords[i*4+2], l2 = coords[i*4+1];
  int id = (l0*D + l1)*D + l2;
  g[id] = sdf[i];
  gt[id] = sdft[i];
  occ[id] = 1;
}

__global__ void k_cellok(const uint8_t* __restrict__ occ, uint8_t* __restrict__ cellok) {
  int i = blockIdx.x * blockDim.x + threadIdx.x;
  if (i >= D3) return;
  int c2 = i % D, c1 = (i / D) % D, c0 = i / (D * D);
  uint8_t ok = 0;
  if (c0 <= D-2 && c1 <= D-2 && c2 <= D-2) {
    ok = occ[i] & occ[i+1] & occ[i+D] & occ[i+D+1]
       & occ[i+D*D] & occ[i+D*D+1] & occ[i+D*D+D] & occ[i+D*D+D+1];
  }
  cellok[i] = ok;
}

__device__ __forceinline__ float nval(const uint8_t* occ, const float* gr, int a, int b, int c) {
  int id = (a*D + b)*D + c;
  return occ[id] ? gr[id] : 0.0f;
}

__global__ void k_normals(const int* __restrict__ coords, const uint8_t* __restrict__ occ,
                          const float* __restrict__ g, const float* __restrict__ gt,
                          const float* __restrict__ viewm,
                          float* __restrict__ ngrid, float* __restrict__ ntgrid) {
  int i = blockIdx.x * blockDim.x + threadIdx.x;
  if (i >= NPTS) return;
  int l0 = coords[i*4+3], l1 = coords[i*4+2], l2 = coords[i*4+1];
  bool interior = (l0>=1) & (l0<D-1) & (l1>=1) & (l1<D-1) & (l2>=1) & (l2<D-1);
  int zp = min(l2+1, D-1), zm = max(l2-1, 0);
  int yp = min(l1+1, D-1), ym = max(l1-1, 0);
  int xp = min(l0+1, D-1), xm = max(l0-1, 0);
  float R00 = viewm[0], R01 = viewm[1], R02 = viewm[2];
  float R10 = viewm[4], R11 = viewm[5], R12 = viewm[6];
  float R20 = viewm[8], R21 = viewm[9], R22 = viewm[10];
  int id = (l0*D + l1)*D + l2;
  // grid of sdf (zero background)
  {
    float nx = nval(occ, g, l0, l1, zp) - nval(occ, g, l0, l1, zm);
    float ny = nval(occ, g, l0, yp, l2) - nval(occ, g, l0, ym, l2);
    float nz = nval(occ, g, xp, l1, l2) - nval(occ, g, xm, l1, l2);
    if (!interior) { nx = 0.f; ny = 0.f; nz = 0.f; }
    float r0 = R00*nx + R01*ny + R02*nz;
    float r1 = R10*nx + R11*ny + R12*nz;
    float r2 = R20*nx + R21*ny + R22*nz;
    float nrm = sqrtf(r0*r0 + r1*r1 + r2*r2);
    float inv = -1.0f / fmaxf(nrm, EPSN);
    ngrid[id*3+0] = r0*inv; ngrid[id*3+1] = r1*inv; ngrid[id*3+2] = r2*inv;
  }
  {
    float nx = nval(occ, gt, l0, l1, zp) - nval(occ, gt, l0, l1, zm);
    float ny = nval(occ, gt, l0, yp, l2) - nval(occ, gt, l0, ym, l2);
    float nz = nval(occ, gt, xp, l1, l2) - nval(occ, gt, xm, l1, l2);
    if (!interior) { nx = 0.f; ny = 0.f; nz = 0.f; }
    float r0 = R00*nx + R01*ny + R02*nz;
    float r1 = R10*nx + R11*ny + R12*nz;
    float r2 = R20*nx + R21*ny + R22*nz;
    float nrm = sqrtf(r0*r0 + r1*r1 + r2*r2);
    float inv = -1.0f / fmaxf(nrm, EPSN);
    ntgrid[id*3+0] = r0*inv; ntgrid[id*3+1] = r1*inv; ntgrid[id*3+2] = r2*inv;
  }
}

__global__ void __launch_bounds__(256) k_raycast(
    const float* __restrict__ g, const float* __restrict__ gt,
    const uint8_t* __restrict__ cellok,
    const float* __restrict__ ngrid, const float* __restrict__ ntgrid,
    const float* __restrict__ viewm, const float* __restrict__ intrm,
    const float* __restrict__ origin,
    float* __restrict__ out_depth, float* __restrict__ out_n, float* __restrict__ out_nt,
    uint8_t* __restrict__ hit0, uint8_t* __restrict__ hit1) {
  int p = blockIdx.x * blockDim.x + threadIdx.x;
  if (p >= HW) return;
  int zsel = blockIdx.z;
  const float* sdfg = zsel ? gt : g;
  const float* ng = zsel ? ntgrid : ngrid;

  float u = (float)(p % IMW), v = (float)(p / IMW);
  float fx = intrm[0], fy = intrm[5], cx = intrm[2], cy = intrm[6];
  float dc0 = (u - cx) / fx, dc1 = (v - cy) / fy, dc2 = 1.0f;
  // d_w = R^T d_c   (R = view[:3,:3])
  float dw0 = viewm[0]*dc0 + viewm[4]*dc1 + viewm[8]*dc2;
  float dw1 = viewm[1]*dc0 + viewm[5]*dc1 + viewm[9]*dc2;
  float dw2 = viewm[2]*dc0 + viewm[6]*dc1 + viewm[10]*dc2;
  float nrm = sqrtf(dw0*dw0 + dw1*dw1 + dw2*dw2);
  dw0 /= nrm; dw1 /= nrm; dw2 /= nrm;
  // tcw = -R^T t
  float tc0 = -(viewm[0]*viewm[3] + viewm[4]*viewm[7] + viewm[8]*viewm[11]);
  float tc1 = -(viewm[1]*viewm[3] + viewm[5]*viewm[7] + viewm[9]*viewm[11]);
  float tc2 = -(viewm[2]*viewm[3] + viewm[6]*viewm[7] + viewm[10]*viewm[11]);
  float cam0 = (tc0 - origin[0]) / VOXEL;
  float cam1 = (tc1 - origin[1]) / VOXEL;
  float cam2 = (tc2 - origin[2]) / VOXEL;

  float prev_s = TRUNC;
  bool prev_ok = false, hit = false;
  float t_hit = 0.0f;
  for (int st = 0; st < NSTEPS; ++st) {
    float t = DEPTHMIN + RAYINC * (float)st;
    float p0f = cam0 + t*dw0, p1f = cam1 + t*dw1, p2f = cam2 + t*dw2;
    float f0 = floorf(p0f), f1 = floorf(p1f), f2 = floorf(p2f);
    int c0 = (int)f0, c1 = (int)f1, c2 = (int)f2;
    bool ok = false;
    float s = 0.f;
    if (c0 >= 0 && c0 <= D-2 && c1 >= 0 && c1 <= D-2 && c2 >= 0 && c2 <= D-2) {
      int base = (c0*D + c1)*D + c2;
      if (cellok[base]) {
        ok = true;
        float a0 = p0f - f0, a1 = p1f - f1, a2 = p2f - f2;
        float b0 = 1.f - a0, b1 = 1.f - a1, b2 = 1.f - a2;
        s = b0*b1*b2*sdfg[base]
          + b0*b1*a2*sdfg[base+1]
          + b0*a1*b2*sdfg[base+D]
          + b0*a1*a2*sdfg[base+D+1]
          + a0*b1*b2*sdfg[base+D*D]
          + a0*b1*a2*sdfg[base+D*D+1]
          + a0*a1*b2*sdfg[base+D*D+D]
          + a0*a1*a2*sdfg[base+D*D+D+1];
        if (prev_ok && prev_s > 0.f && s <= 0.f) {
          float denom = prev_s - s;
          if (fabsf(denom) < 1e-8f) denom = 1e-8f;
          t_hit = t - RAYINC + RAYINC * (prev_s / denom);
          hit = true;
          break;
        }
      }
    }
    prev_ok = ok;
    prev_s = s;
  }

  float depth = hit ? t_hit * VOXEL : 0.0f;
  float n0 = 0.f, n1 = 0.f, n2 = 0.f;
  if (hit) {
    float ph0 = cam0 + t_hit*dw0, ph1 = cam1 + t_hit*dw1, ph2 = cam2 + t_hit*dw2;
    int q0 = min(max((int)rintf(ph0), 0), D-1);
    int q1 = min(max((int)rintf(ph1), 0), D-1);
    int q2 = min(max((int)rintf(ph2), 0), D-1);
    int nid = ((q0*D + q1)*D + q2) * 3;
    n0 = ng[nid]; n1 = ng[nid+1]; n2 = ng[nid+2];
  }
  if (zsel == 0) {
    out_depth[p] = depth;
    out_n[p*3+0] = n0; out_n[p*3+1] = n1; out_n[p*3+2] = n2;
    hit0[p] = hit ? 1 : 0;
  } else {
    out_nt[p*3+0] = n0; out_nt[p*3+1] = n1; out_nt[p*3+2] = n2;
    hit1[p] = hit ? 1 : 0;
  }
}

__global__ void k_init_sc(Scal* sc) {
  sc->minD = __float_as_uint(1e9f);
  sc->maxD = 0u;
  sc->minT = __float_as_uint(1e9f);
  sc->maxT = 0u;
  sc->cntM = 0u; sc->cntN = 0u;
  sc->sumD = 0.f; sc->sumN = 0.f;
}

__global__ void k_red1(const uint8_t* __restrict__ hit0, const uint8_t* __restrict__ hit1,
                       const float* __restrict__ dimg, const float* __restrict__ dt,
                       Scal* sc) {
  int p = blockIdx.x * blockDim.x + threadIdx.x;
  float lminD = 1e9f, lmaxD = 0.f, lminT = 1e9f, lmaxT = 0.f;
  unsigned lcntM = 0, lcntN = 0;
  if (p < HW) {
    bool h = hit0[p] != 0;
    float dtv = dt[p];
    if (h && dtv != 0.f) {
      float dv = dimg[p];
      lminD = dv; lmaxD = dv; lminT = dtv; lmaxT = dtv; lcntM = 1;
    }
    if (h && hit1[p] != 0) lcntN = 1;
  }
  for (int off = 32; off > 0; off >>= 1) {
    lminD = fminf(lminD, __shfl_down(lminD, off));
    lmaxD = fmaxf(lmaxD, __shfl_down(lmaxD, off));
    lminT = fminf(lminT, __shfl_down(lminT, off));
    lmaxT = fmaxf(lmaxT, __shfl_down(lmaxT, off));
    lcntM += __shfl_down(lcntM, off);
    lcntN += __shfl_down(lcntN, off);
  }
  if ((threadIdx.x & 63) == 0) {
    atomicMin(&sc->minD, __float_as_uint(lminD));
    atomicMax(&sc->maxD, __float_as_uint(lmaxD));
    atomicMin(&sc->minT, __float_as_uint(lminT));
    atomicMax(&sc->maxT, __float_as_uint(lmaxT));
    if (lcntM) atomicAdd(&sc->cntM, lcntM);
    if (lcntN) atomicAdd(&sc->cntN, lcntN);
  }
}

__global__ void k_red2(const uint8_t* __restrict__ hit0, const uint8_t* __restrict__ hit1,
                       const float* __restrict__ dimg, const float* __restrict__ dt,
                       const float* __restrict__ nimg, const float* __restrict__ ntimg,
                       Scal* sc) {
  int p = blockIdx.x * blockDim.x + threadIdx.x;
  float sD = 0.f, sN = 0.f;
  if (p < HW) {
    bool h = hit0[p] != 0;
    float dtv = dt[p];
    if (h && dtv != 0.f) {
      float vminD = __uint_as_float(sc->minD);
      float vmaxD = __uint_as_float(sc->maxD) - vminD;
      float denD = (vmaxD <= 0.f) ? 1.f : vmaxD;
      float vminT = __uint_as_float(sc->minT);
      float vmaxT = __uint_as_float(sc->maxT) - vminT;
      float denT = (vmaxT <= 0.f) ? 1.f : vmaxT;
      sD = fabsf((dimg[p] - vminD) / denD - (dtv - vminT) / denT);
    }
    if (h && hit1[p] != 0) {
      sN = fabsf(nimg[p*3+0] - ntimg[p*3+0])
         + fabsf(nimg[p*3+1] - ntimg[p*3+1])
         + fabsf(nimg[p*3+2] - ntimg[p*3+2]);
    }
  }
  for (int off = 32; off > 0; off >>= 1) {
    sD += __shfl_down(sD, off);
    sN += __shfl_down(sN, off);
  }
  if ((threadIdx.x & 63) == 0) {
    if (sD != 0.f) atomicAdd(&sc->sumD, sD);
    if (sN != 0.f) atomicAdd(&sc->sumN, sN);
  }
}

__global__ void k_fin_view(Scal* sc) {
  float ld = (sc->cntM > 0) ? sc->sumD / (float)sc->cntM : 0.f;
  float ln = (sc->cntN > 0) ? sc->sumN / (float)(3u * sc->cntN) : 0.f;
  sc->lossD += ld * 0.5f;  // WEIGHT / N_VIEWS
  sc->lossN += ln * 0.5f;
}

__global__ void k_write_loss(const Scal* __restrict__ sc, float* __restrict__ out) {
  out[0] = sc->lossD;
  out[1] = sc->lossN;
}

__global__ void k_copy(const float* __restrict__ src, float* __restrict__ dst, int n) {
  int i = blockIdx.x * blockDim.x + threadIdx.x;
  if (i < n) dst[i] = src[i];
}

extern "C" void kernel_launch(void* const* d_in, const int* in_sizes, int n_in,
                              void* d_out, int out_size, void* d_ws, size_t ws_size,
                              hipStream_t stream) {
  const int*   coords = (const int*)d_in[0];
  const float* origin = (const float*)d_in[1];
  const float* sdf    = (const float*)d_in[2];
  const float* sdft   = (const float*)d_in[3];
  const float* dt     = (const float*)d_in[4];
  const float* intr   = (const float*)d_in[5];
  const float* viewm  = (const float*)d_in[6];
  float* out = (float*)d_out;

  // workspace layout
  char* w = (char*)d_ws;
  uint8_t* occ    = (uint8_t*)w;                    // D3 bytes
  uint8_t* cellok = occ + D3;                       // D3 bytes
  float* g      = (float*)(w + 2*(size_t)D3);       // D3 f32
  float* gt     = g + D3;                           // D3 f32
  float* ngrid  = gt + D3;                          // 3*D3 f32
  float* ntgrid = ngrid + 3*(size_t)D3;             // 3*D3 f32
  uint8_t* hit0 = (uint8_t*)(ntgrid + 3*(size_t)D3);// HW bytes
  uint8_t* hit1 = hit0 + HW;                        // HW bytes
  Scal* sc = (Scal*)(hit1 + HW);

  // output layout
  float* out_depths = out + 2;                 // 2*HW
  float* out_dt     = out + 2 + 2*(size_t)HW;  // 2*HW
  float* out_norm   = out + 2 + 4*(size_t)HW;  // 2*HW*3
  float* out_normt  = out + 2 + 10*(size_t)HW; // 2*HW*3

  hipMemsetAsync(occ, 0, D3, stream);
  hipMemsetAsync(ngrid, 0, 6*(size_t)D3*sizeof(float), stream);
  k_fill<<<(D3+255)/256, 256, 0, stream>>>(g, gt, sc);
  k_scatter<<<(NPTS+255)/256, 256, 0, stream>>>(coords, sdf, sdft, g, gt, occ);
  k_cellok<<<(D3+255)/256, 256, 0, stream>>>(occ, cellok);
  k_copy<<<(2*HW+255)/256, 256, 0, stream>>>(dt, out_dt, 2*HW);

  for (int v = 0; v < 2; ++v) {
    const float* vm = viewm + v*16;
    const float* km = intr + v*16;
    const float* dtv = dt + (size_t)v*HW;
    float* od  = out_depths + (size_t)v*HW;
    float* on  = out_norm  + (size_t)v*HW*3;
    float* ont = out_normt + (size_t)v*HW*3;

    k_normals<<<(NPTS+255)/256, 256, 0, stream>>>(coords, occ, g, gt, vm, ngrid, ntgrid);
    k_raycast<<<dim3((HW+255)/256, 1, 2), 256, 0, stream>>>(
        g, gt, cellok, ngrid, ntgrid, vm, km, origin, od, on, ont, hit0, hit1);
    k_init_sc<<<1, 1, 0, stream>>>(sc);
    k_red1<<<(HW+255)/256, 256, 0, stream>>>(hit0, hit1, od, dtv, sc);
    k_red2<<<(HW+255)/256, 256, 0, stream>>>(hit0, hit1, od, dtv, on, ont, sc);
    k_fin_view<<<1, 1, 0, stream>>>(sc);
  }
  k_write_loss<<<1, 1, 0, stream>>>(sc, out);
}

// Round 2
// 260.847 us; speedup vs baseline: 2.6069x; 2.6069x over previous
//
#include <hip/hip_runtime.h>
#include <stdint.h>

#define D 96
#define D3 (96*96*96)
#define IMW 640
#define IMH 480
#define HW (IMW*IMH)
#define NPTS 150000
#define VOXEL 0.04f
#define TRUNC 5.0f
#define RAYINC 1.5f
#define DEPTHMIN 0.025f
#define NSTEPS 67
#define EPSN 1e-5f
#define RED_BLOCKS 240

struct Scal {
  unsigned minD, maxD, minT, maxT, cntM, cntN;
  float sumD, sumN;
};

__global__ void k_fill(float* __restrict__ g, float* __restrict__ gt, Scal* sc) {
  int i = blockIdx.x * blockDim.x + threadIdx.x;
  if (i < D3) { g[i] = TRUNC; gt[i] = TRUNC; }
  if (i < 2) {
    sc[i].minD = __float_as_uint(1e9f);
    sc[i].maxD = 0u;
    sc[i].minT = __float_as_uint(1e9f);
    sc[i].maxT = 0u;
    sc[i].cntM = 0u; sc[i].cntN = 0u;
    sc[i].sumD = 0.f; sc[i].sumN = 0.f;
  }
}

__global__ void k_scatter(const int* __restrict__ coords, const float* __restrict__ sdf,
                          const float* __restrict__ sdft,
                          float* __restrict__ g, float* __restrict__ gt,
                          uint8_t* __restrict__ occ) {
  int i = blockIdx.x * blockDim.x + threadIdx.x;
  if (i >= NPTS) return;
  int l0 = coords[i*4+3], l1 = coords[i*4+2], l2 = coords[i*4+1];
  int id = (l0*D + l1)*D + l2;
  g[id] = sdf[i];
  gt[id] = sdft[i];
  occ[id] = 1;
}

__global__ void k_cellok(const uint8_t* __restrict__ occ, uint8_t* __restrict__ cellok) {
  int i = blockIdx.x * blockDim.x + threadIdx.x;
  if (i >= D3) return;
  int c2 = i % D, c1 = (i / D) % D, c0 = i / (D * D);
  uint8_t ok = 0;
  if (c0 <= D-2 && c1 <= D-2 && c2 <= D-2) {
    ok = occ[i] & occ[i+1] & occ[i+D] & occ[i+D+1]
       & occ[i+D*D] & occ[i+D*D+1] & occ[i+D*D+D] & occ[i+D*D+D+1];
  }
  cellok[i] = ok;
}

__device__ __forceinline__ float nval(const uint8_t* occ, const float* gr, int a, int b, int c) {
  int id = (a*D + b)*D + c;
  return occ[id] ? gr[id] : 0.0f;
}

__global__ void k_normals(const int* __restrict__ coords, const uint8_t* __restrict__ occ,
                          const float* __restrict__ g, const float* __restrict__ gt,
                          const float* __restrict__ viewm,
                          float* __restrict__ ngrid, float* __restrict__ ntgrid) {
  int i = blockIdx.x * blockDim.x + threadIdx.x;
  if (i >= NPTS) return;
  int l0 = coords[i*4+3], l1 = coords[i*4+2], l2 = coords[i*4+1];
  bool interior = (l0>=1) & (l0<D-1) & (l1>=1) & (l1<D-1) & (l2>=1) & (l2<D-1);
  int zp = min(l2+1, D-1), zm = max(l2-1, 0);
  int yp = min(l1+1, D-1), ym = max(l1-1, 0);
  int xp = min(l0+1, D-1), xm = max(l0-1, 0);
  float R00 = viewm[0], R01 = viewm[1], R02 = viewm[2];
  float R10 = viewm[4], R11 = viewm[5], R12 = viewm[6];
  float R20 = viewm[8], R21 = viewm[9], R22 = viewm[10];
  int id = (l0*D + l1)*D + l2;
  {
    float nx = nval(occ, g, l0, l1, zp) - nval(occ, g, l0, l1, zm);
    float ny = nval(occ, g, l0, yp, l2) - nval(occ, g, l0, ym, l2);
    float nz = nval(occ, g, xp, l1, l2) - nval(occ, g, xm, l1, l2);
    if (!interior) { nx = 0.f; ny = 0.f; nz = 0.f; }
    float r0 = R00*nx + R01*ny + R02*nz;
    float r1 = R10*nx + R11*ny + R12*nz;
    float r2 = R20*nx + R21*ny + R22*nz;
    float nrm = sqrtf(r0*r0 + r1*r1 + r2*r2);
    float inv = -1.0f / fmaxf(nrm, EPSN);
    ngrid[id*3+0] = r0*inv; ngrid[id*3+1] = r1*inv; ngrid[id*3+2] = r2*inv;
  }
  {
    float nx = nval(occ, gt, l0, l1, zp) - nval(occ, gt, l0, l1, zm);
    float ny = nval(occ, gt, l0, yp, l2) - nval(occ, gt, l0, ym, l2);
    float nz = nval(occ, gt, xp, l1, l2) - nval(occ, gt, xm, l1, l2);
    if (!interior) { nx = 0.f; ny = 0.f; nz = 0.f; }
    float r0 = R00*nx + R01*ny + R02*nz;
    float r1 = R10*nx + R11*ny + R12*nz;
    float r2 = R20*nx + R21*ny + R22*nz;
    float nrm = sqrtf(r0*r0 + r1*r1 + r2*r2);
    float inv = -1.0f / fmaxf(nrm, EPSN);
    ntgrid[id*3+0] = r0*inv; ntgrid[id*3+1] = r1*inv; ntgrid[id*3+2] = r2*inv;
  }
}

__global__ void __launch_bounds__(256) k_raycast(
    const float* __restrict__ g, const float* __restrict__ gt,
    const uint8_t* __restrict__ cellok,
    const float* __restrict__ ngrid, const float* __restrict__ ntgrid,
    const float* __restrict__ viewm, const float* __restrict__ intrm,
    const float* __restrict__ origin,
    float* __restrict__ out_depth, float* __restrict__ out_n, float* __restrict__ out_nt,
    uint8_t* __restrict__ hit0, uint8_t* __restrict__ hit1) {
  int p = blockIdx.x * blockDim.x + threadIdx.x;
  if (p >= HW) return;
  int zsel = blockIdx.z;
  const float* sdfg = zsel ? gt : g;
  const float* ng = zsel ? ntgrid : ngrid;

  float u = (float)(p % IMW), v = (float)(p / IMW);
  float fx = intrm[0], fy = intrm[5], cx = intrm[2], cy = intrm[6];
  float dc0 = (u - cx) / fx, dc1 = (v - cy) / fy, dc2 = 1.0f;
  float dw0 = viewm[0]*dc0 + viewm[4]*dc1 + viewm[8]*dc2;
  float dw1 = viewm[1]*dc0 + viewm[5]*dc1 + viewm[9]*dc2;
  float dw2 = viewm[2]*dc0 + viewm[6]*dc1 + viewm[10]*dc2;
  float nrm = sqrtf(dw0*dw0 + dw1*dw1 + dw2*dw2);
  dw0 /= nrm; dw1 /= nrm; dw2 /= nrm;
  float tc0 = -(viewm[0]*viewm[3] + viewm[4]*viewm[7] + viewm[8]*viewm[11]);
  float tc1 = -(viewm[1]*viewm[3] + viewm[5]*viewm[7] + viewm[9]*viewm[11]);
  float tc2 = -(viewm[2]*viewm[3] + viewm[6]*viewm[7] + viewm[10]*viewm[11]);
  float cam0 = (tc0 - origin[0]) / VOXEL;
  float cam1 = (tc1 - origin[1]) / VOXEL;
  float cam2 = (tc2 - origin[2]) / VOXEL;

  float prev_s = TRUNC;
  bool prev_ok = false, hit = false;
  float t_hit = 0.0f;
  for (int st = 0; st < NSTEPS; ++st) {
    float t = DEPTHMIN + RAYINC * (float)st;
    float p0f = cam0 + t*dw0, p1f = cam1 + t*dw1, p2f = cam2 + t*dw2;
    float f0 = floorf(p0f), f1 = floorf(p1f), f2 = floorf(p2f);
    int c0 = (int)f0, c1 = (int)f1, c2 = (int)f2;
    bool ok = false;
    float s = 0.f;
    if (c0 >= 0 && c0 <= D-2 && c1 >= 0 && c1 <= D-2 && c2 >= 0 && c2 <= D-2) {
      int base = (c0*D + c1)*D + c2;
      if (cellok[base]) {
        ok = true;
        float a0 = p0f - f0, a1 = p1f - f1, a2 = p2f - f2;
        float b0 = 1.f - a0, b1 = 1.f - a1, b2 = 1.f - a2;
        s = b0*b1*b2*sdfg[base]
          + b0*b1*a2*sdfg[base+1]
          + b0*a1*b2*sdfg[base+D]
          + b0*a1*a2*sdfg[base+D+1]
          + a0*b1*b2*sdfg[base+D*D]
          + a0*b1*a2*sdfg[base+D*D+1]
          + a0*a1*b2*sdfg[base+D*D+D]
          + a0*a1*a2*sdfg[base+D*D+D+1];
        if (prev_ok && prev_s > 0.f && s <= 0.f) {
          float denom = prev_s - s;
          if (fabsf(denom) < 1e-8f) denom = 1e-8f;
          t_hit = t - RAYINC + RAYINC * (prev_s / denom);
          hit = true;
          break;
        }
      }
    }
    prev_ok = ok;
    prev_s = s;
  }

  float depth = hit ? t_hit * VOXEL : 0.0f;
  float n0 = 0.f, n1 = 0.f, n2 = 0.f;
  if (hit) {
    float ph0 = cam0 + t_hit*dw0, ph1 = cam1 + t_hit*dw1, ph2 = cam2 + t_hit*dw2;
    int q0 = min(max((int)rintf(ph0), 0), D-1);
    int q1 = min(max((int)rintf(ph1), 0), D-1);
    int q2 = min(max((int)rintf(ph2), 0), D-1);
    int nid = ((q0*D + q1)*D + q2) * 3;
    n0 = ng[nid]; n1 = ng[nid+1]; n2 = ng[nid+2];
  }
  if (zsel == 0) {
    out_depth[p] = depth;
    out_n[p*3+0] = n0; out_n[p*3+1] = n1; out_n[p*3+2] = n2;
    hit0[p] = hit ? 1 : 0;
  } else {
    out_nt[p*3+0] = n0; out_nt[p*3+1] = n1; out_nt[p*3+2] = n2;
    hit1[p] = hit ? 1 : 0;
  }
}

__global__ void __launch_bounds__(256) k_red1(
    const uint8_t* __restrict__ hit0, const uint8_t* __restrict__ hit1,
    const float* __restrict__ dimg, const float* __restrict__ dt,
    Scal* __restrict__ sc) {
  __shared__ float sminD[4], smaxD[4], sminT[4], smaxT[4];
  __shared__ unsigned scntM[4], scntN[4];
  float lminD = 1e9f, lmaxD = 0.f, lminT = 1e9f, lmaxT = 0.f;
  unsigned lcntM = 0, lcntN = 0;
  for (int p = blockIdx.x * blockDim.x + threadIdx.x; p < HW;
       p += gridDim.x * blockDim.x) {
    bool h = hit0[p] != 0;
    float dtv = dt[p];
    if (h && dtv != 0.f) {
      float dv = dimg[p];
      lminD = fminf(lminD, dv); lmaxD = fmaxf(lmaxD, dv);
      lminT = fminf(lminT, dtv); lmaxT = fmaxf(lmaxT, dtv);
      lcntM++;
    }
    if (h && hit1[p] != 0) lcntN++;
  }
  for (int off = 32; off > 0; off >>= 1) {
    lminD = fminf(lminD, __shfl_down(lminD, off));
    lmaxD = fmaxf(lmaxD, __shfl_down(lmaxD, off));
    lminT = fminf(lminT, __shfl_down(lminT, off));
    lmaxT = fmaxf(lmaxT, __shfl_down(lmaxT, off));
    lcntM += __shfl_down(lcntM, off);
    lcntN += __shfl_down(lcntN, off);
  }
  int wid = threadIdx.x >> 6;
  if ((threadIdx.x & 63) == 0) {
    sminD[wid] = lminD; smaxD[wid] = lmaxD;
    sminT[wid] = lminT; smaxT[wid] = lmaxT;
    scntM[wid] = lcntM; scntN[wid] = lcntN;
  }
  __syncthreads();
  if (threadIdx.x == 0) {
    float mnD = sminD[0], mxD = smaxD[0], mnT = sminT[0], mxT = smaxT[0];
    unsigned cM = scntM[0], cN = scntN[0];
    for (int w = 1; w < 4; ++w) {
      mnD = fminf(mnD, sminD[w]); mxD = fmaxf(mxD, smaxD[w]);
      mnT = fminf(mnT, sminT[w]); mxT = fmaxf(mxT, smaxT[w]);
      cM += scntM[w]; cN += scntN[w];
    }
    atomicMin(&sc->minD, __float_as_uint(mnD));
    atomicMax(&sc->maxD, __float_as_uint(mxD));
    atomicMin(&sc->minT, __float_as_uint(mnT));
    atomicMax(&sc->maxT, __float_as_uint(mxT));
    if (cM) atomicAdd(&sc->cntM, cM);
    if (cN) atomicAdd(&sc->cntN, cN);
  }
}

__global__ void __launch_bounds__(256) k_red2(
    const uint8_t* __restrict__ hit0, const uint8_t* __restrict__ hit1,
    const float* __restrict__ dimg, const float* __restrict__ dt,
    const float* __restrict__ nimg, const float* __restrict__ ntimg,
    Scal* __restrict__ sc) {
  __shared__ float ssD[4], ssN[4];
  float vminD = __uint_as_float(sc->minD);
  float vmaxD = __uint_as_float(sc->maxD) - vminD;
  float denD = (vmaxD <= 0.f) ? 1.f : vmaxD;
  float vminT = __uint_as_float(sc->minT);
  float vmaxT = __uint_as_float(sc->maxT) - vminT;
  float denT = (vmaxT <= 0.f) ? 1.f : vmaxT;
  float sD = 0.f, sN = 0.f;
  for (int p = blockIdx.x * blockDim.x + threadIdx.x; p < HW;
       p += gridDim.x * blockDim.x) {
    bool h = hit0[p] != 0;
    float dtv = dt[p];
    if (h && dtv != 0.f) {
      sD += fabsf((dimg[p] - vminD) / denD - (dtv - vminT) / denT);
    }
    if (h && hit1[p] != 0) {
      sN += fabsf(nimg[p*3+0] - ntimg[p*3+0])
          + fabsf(nimg[p*3+1] - ntimg[p*3+1])
          + fabsf(nimg[p*3+2] - ntimg[p*3+2]);
    }
  }
  for (int off = 32; off > 0; off >>= 1) {
    sD += __shfl_down(sD, off);
    sN += __shfl_down(sN, off);
  }
  int wid = threadIdx.x >> 6;
  if ((threadIdx.x & 63) == 0) { ssD[wid] = sD; ssN[wid] = sN; }
  __syncthreads();
  if (threadIdx.x == 0) {
    float tD = ssD[0] + ssD[1] + ssD[2] + ssD[3];
    float tN = ssN[0] + ssN[1] + ssN[2] + ssN[3];
    if (tD != 0.f) atomicAdd(&sc->sumD, tD);
    if (tN != 0.f) atomicAdd(&sc->sumN, tN);
  }
}

__global__ void k_write_loss(const Scal* __restrict__ sc, float* __restrict__ out) {
  float lossD = 0.f, lossN = 0.f;
  for (int v = 0; v < 2; ++v) {
    float ld = (sc[v].cntM > 0) ? sc[v].sumD / (float)sc[v].cntM : 0.f;
    float ln = (sc[v].cntN > 0) ? sc[v].sumN / (float)(3u * sc[v].cntN) : 0.f;
    lossD += ld * 0.5f;  // WEIGHT / N_VIEWS
    lossN += ln * 0.5f;
  }
  out[0] = lossD;
  out[1] = lossN;
}

__global__ void k_copy(const float* __restrict__ src, float* __restrict__ dst, int n) {
  int i = blockIdx.x * blockDim.x + threadIdx.x;
  if (i < n) dst[i] = src[i];
}

extern "C" void kernel_launch(void* const* d_in, const int* in_sizes, int n_in,
                              void* d_out, int out_size, void* d_ws, size_t ws_size,
                              hipStream_t stream) {
  const int*   coords = (const int*)d_in[0];
  const float* origin = (const float*)d_in[1];
  const float* sdf    = (const float*)d_in[2];
  const float* sdft   = (const float*)d_in[3];
  const float* dt     = (const float*)d_in[4];
  const float* intr   = (const float*)d_in[5];
  const float* viewm  = (const float*)d_in[6];
  float* out = (float*)d_out;

  char* w = (char*)d_ws;
  uint8_t* occ    = (uint8_t*)w;                    // D3 bytes
  uint8_t* cellok = occ + D3;                       // D3 bytes
  float* g      = (float*)(w + 2*(size_t)D3);       // D3 f32
  float* gt     = g + D3;                           // D3 f32
  float* ngrid  = gt + D3;                          // 3*D3 f32
  float* ntgrid = ngrid + 3*(size_t)D3;             // 3*D3 f32
  uint8_t* hit0 = (uint8_t*)(ntgrid + 3*(size_t)D3);// HW bytes
  uint8_t* hit1 = hit0 + HW;                        // HW bytes
  Scal* sc = (Scal*)(hit1 + HW);                    // 2 structs

  float* out_depths = out + 2;                 // 2*HW
  float* out_dt     = out + 2 + 2*(size_t)HW;  // 2*HW
  float* out_norm   = out + 2 + 4*(size_t)HW;  // 2*HW*3
  float* out_normt  = out + 2 + 10*(size_t)HW; // 2*HW*3

  hipMemsetAsync(occ, 0, D3, stream);
  hipMemsetAsync(ngrid, 0, 6*(size_t)D3*sizeof(float), stream);
  k_fill<<<(D3+255)/256, 256, 0, stream>>>(g, gt, sc);
  k_scatter<<<(NPTS+255)/256, 256, 0, stream>>>(coords, sdf, sdft, g, gt, occ);
  k_cellok<<<(D3+255)/256, 256, 0, stream>>>(occ, cellok);
  k_copy<<<(2*HW+255)/256, 256, 0, stream>>>(dt, out_dt, 2*HW);

  for (int v = 0; v < 2; ++v) {
    const float* vm = viewm + v*16;
    const float* km = intr + v*16;
    const float* dtv = dt + (size_t)v*HW;
    float* od  = out_depths + (size_t)v*HW;
    float* on  = out_norm  + (size_t)v*HW*3;
    float* ont = out_normt + (size_t)v*HW*3;

    k_normals<<<(NPTS+255)/256, 256, 0, stream>>>(coords, occ, g, gt, vm, ngrid, ntgrid);
    k_raycast<<<dim3((HW+255)/256, 1, 2), 256, 0, stream>>>(
        g, gt, cellok, ngrid, ntgrid, vm, km, origin, od, on, ont, hit0, hit1);
    k_red1<<<RED_BLOCKS, 256, 0, stream>>>(hit0, hit1, od, dtv, sc + v);
    k_red2<<<RED_BLOCKS, 256, 0, stream>>>(hit0, hit1, od, dtv, on, ont, sc + v);
  }
  k_write_loss<<<1, 1, 0, stream>>>(sc, out);
}

// Round 3
// 165.212 us; speedup vs baseline: 4.1160x; 1.5789x over previous
//
#include <hip/hip_runtime.h>
#include <stdint.h>

#define D 96
#define D2 (96*96)
#define D3 (96*96*96)
#define IMW 640
#define IMH 480
#define HW (IMW*IMH)
#define NPTS 150000
#define VOXEL 0.04f
#define TRUNC 5.0f
#define RAYINC 1.5f
#define DEPTHMIN 0.025f
#define NSTEPS 67
#define EPSN 1e-5f
#define RED_BLOCKS 240

struct Scal {
  unsigned minD, maxD, minT, maxT, cntM, cntN;
  float sumD, sumN;
};

// ws: g, gt (f32 D3 each), coarse (8^3 u32), sc (2), occ, cellok (u8 D3), hit0, hit1 (u8 2*HW)

__global__ void k_init(float* __restrict__ g, float* __restrict__ gt,
                       uint8_t* __restrict__ occ, uint32_t* __restrict__ coarse,
                       Scal* __restrict__ sc) {
  int i = blockIdx.x * blockDim.x + threadIdx.x;
  if (i < D3) { g[i] = TRUNC; gt[i] = TRUNC; occ[i] = 0; }
  if (i < 512) coarse[i] = 0u;
  if (i < 2) {
    sc[i].minD = __float_as_uint(1e9f);
    sc[i].maxD = 0u;
    sc[i].minT = __float_as_uint(1e9f);
    sc[i].maxT = 0u;
    sc[i].cntM = 0u; sc[i].cntN = 0u;
    sc[i].sumD = 0.f; sc[i].sumN = 0.f;
  }
}

__global__ void k_scatter(const int* __restrict__ coords, const float* __restrict__ sdf,
                          const float* __restrict__ sdft,
                          float* __restrict__ g, float* __restrict__ gt,
                          uint8_t* __restrict__ occ) {
  int i = blockIdx.x * blockDim.x + threadIdx.x;
  if (i >= NPTS) return;
  int l0 = coords[i*4+3], l1 = coords[i*4+2], l2 = coords[i*4+1];
  int id = (l0*D + l1)*D + l2;
  g[id] = sdf[i];
  gt[id] = sdft[i];
  occ[id] = 1;
}

__global__ void k_cellok(const uint8_t* __restrict__ occ, uint8_t* __restrict__ cellok,
                         uint32_t* __restrict__ coarse) {
  int i = blockIdx.x * blockDim.x + threadIdx.x;
  if (i >= D3) return;
  int c2 = i % D, c1 = (i / D) % D, c0 = i / D2;
  uint8_t ok = 0;
  if (c0 <= D-2 && c1 <= D-2 && c2 <= D-2) {
    ok = occ[i] & occ[i+1] & occ[i+D] & occ[i+D+1]
       & occ[i+D2] & occ[i+D2+1] & occ[i+D2+D] & occ[i+D2+D+1];
  }
  cellok[i] = ok;
  if (ok) {
    // mark coarse block containing this cell (padded 8^3, +1 border)
    int w = ((c0>>4)+1)*64 + ((c1>>4)+1)*8 + ((c2>>4)+1);
    atomicOr(&coarse[w], 1u);
  }
}

__device__ __forceinline__ float nval(const uint8_t* occ, const float* gr, int a, int b, int c) {
  int id = (a*D + b)*D + c;
  return occ[id] ? gr[id] : 0.0f;
}

__global__ void __launch_bounds__(256) k_raycast(
    const float* __restrict__ g, const float* __restrict__ gt,
    const uint8_t* __restrict__ occ, const uint8_t* __restrict__ cellok,
    const uint32_t* __restrict__ coarse,
    const float* __restrict__ viewm_all, const float* __restrict__ intr_all,
    const float* __restrict__ origin,
    float* __restrict__ out_depths, float* __restrict__ out_norm,
    float* __restrict__ out_normt,
    uint8_t* __restrict__ hit0, uint8_t* __restrict__ hit1) {
  int p = blockIdx.x * blockDim.x + threadIdx.x;
  if (p >= HW) return;
  int zb = blockIdx.z;
  int view = zb >> 1, zsel = zb & 1;
  const float* vm = viewm_all + view*16;
  const float* km = intr_all + view*16;
  const float* sdfg = zsel ? gt : g;

  float u = (float)(p % IMW), v = (float)(p / IMW);
  float fx = km[0], fy = km[5], cx = km[2], cy = km[6];
  float dc0 = (u - cx) / fx, dc1 = (v - cy) / fy, dc2 = 1.0f;
  float dw0 = vm[0]*dc0 + vm[4]*dc1 + vm[8]*dc2;
  float dw1 = vm[1]*dc0 + vm[5]*dc1 + vm[9]*dc2;
  float dw2 = vm[2]*dc0 + vm[6]*dc1 + vm[10]*dc2;
  float nrm = sqrtf(dw0*dw0 + dw1*dw1 + dw2*dw2);
  dw0 /= nrm; dw1 /= nrm; dw2 /= nrm;
  float tc0 = -(vm[0]*vm[3] + vm[4]*vm[7] + vm[8]*vm[11]);
  float tc1 = -(vm[1]*vm[3] + vm[5]*vm[7] + vm[9]*vm[11]);
  float tc2 = -(vm[2]*vm[3] + vm[6]*vm[7] + vm[10]*vm[11]);
  float cam0 = (tc0 - origin[0]) / VOXEL;
  float cam1 = (tc1 - origin[1]) / VOXEL;
  float cam2 = (tc2 - origin[2]) / VOXEL;

  // slab clamp of step range against [0,95]^3 (valid-sample region), margin 1 step each side
  float tmin = DEPTHMIN, tmax = DEPTHMIN + RAYINC * (float)(NSTEPS - 1);
  {
    float cams[3] = {cam0, cam1, cam2};
    float dws[3] = {dw0, dw1, dw2};
    #pragma unroll
    for (int a = 0; a < 3; ++a) {
      float dwa = dws[a], cama = cams[a];
      if (fabsf(dwa) < 1e-8f) {
        if (cama < 0.f || cama > 95.f) { tmin = 1e30f; tmax = -1e30f; }
      } else {
        float inv = 1.0f / dwa;
        float t0 = (0.f - cama) * inv, t1 = (95.f - cama) * inv;
        float lo = fminf(t0, t1), hi = fmaxf(t0, t1);
        tmin = fmaxf(tmin, lo); tmax = fminf(tmax, hi);
      }
    }
  }
  int st_lo = NSTEPS, st_hi = 0;
  if (tmax >= tmin) {
    st_lo = (int)ceilf((tmin - DEPTHMIN) / RAYINC) - 1;
    st_lo = max(st_lo, 0);
    st_hi = (int)floorf((tmax - DEPTHMIN) / RAYINC) + 2;
    st_hi = min(st_hi, NSTEPS);
  }

  bool hit = false;
  float t_hit = 0.0f;
  float prev_s = 0.0f;
  int last_ok_st = -5;
  float tf = (float)st_lo;

  #pragma unroll 4
  for (int st = st_lo; st < st_hi; ++st) {
    float t = DEPTHMIN + RAYINC * tf;
    tf += 1.0f;
    float p0f = cam0 + t*dw0, p1f = cam1 + t*dw1, p2f = cam2 + t*dw2;
    int c0 = (int)floorf(p0f), c1 = (int)floorf(p1f), c2 = (int)floorf(p2f);
    int widx = ((c0 >> 4) << 6) + ((c1 >> 4) << 3) + (c2 >> 4) + 73; // +1 border offset
    if (coarse[widx]) {
      if (c0 >= 0 && c0 <= D-2 && c1 >= 0 && c1 <= D-2 && c2 >= 0 && c2 <= D-2) {
        int base = (c0*D + c1)*D + c2;
        if (cellok[base]) {
          float f0 = (float)c0, f1 = (float)c1, f2 = (float)c2;
          float a0 = p0f - f0, a1 = p1f - f1, a2 = p2f - f2;
          float b0 = 1.f - a0, b1 = 1.f - a1, b2 = 1.f - a2;
          float s = b0*b1*b2*sdfg[base]
                  + b0*b1*a2*sdfg[base+1]
                  + b0*a1*b2*sdfg[base+D]
                  + b0*a1*a2*sdfg[base+D+1]
                  + a0*b1*b2*sdfg[base+D2]
                  + a0*b1*a2*sdfg[base+D2+1]
                  + a0*a1*b2*sdfg[base+D2+D]
                  + a0*a1*a2*sdfg[base+D2+D+1];
          if (last_ok_st == st-1 && prev_s > 0.f && s <= 0.f && !hit) {
            float denom = prev_s - s;
            if (fabsf(denom) < 1e-8f) denom = 1e-8f;
            t_hit = t - RAYINC + RAYINC * (prev_s / denom);
            hit = true;
          }
          last_ok_st = st;
          prev_s = s;
        }
      }
    }
  }

  float depth = hit ? t_hit * VOXEL : 0.0f;
  float n0 = 0.f, n1 = 0.f, n2 = 0.f;
  if (hit) {
    float ph0 = cam0 + t_hit*dw0, ph1 = cam1 + t_hit*dw1, ph2 = cam2 + t_hit*dw2;
    int q0 = min(max((int)rintf(ph0), 0), D-1);
    int q1 = min(max((int)rintf(ph1), 0), D-1);
    int q2 = min(max((int)rintf(ph2), 0), D-1);
    int qid = (q0*D + q1)*D + q2;
    if (occ[qid]) {
      // on-demand normal, identical arithmetic to reference _compute_normals_sparse
      bool interior = (q0>=1) & (q0<D-1) & (q1>=1) & (q1<D-1) & (q2>=1) & (q2<D-1);
      int zp = min(q2+1, D-1), zm = max(q2-1, 0);
      int yp = min(q1+1, D-1), ym = max(q1-1, 0);
      int xp = min(q0+1, D-1), xm = max(q0-1, 0);
      float nx = nval(occ, sdfg, q0, q1, zp) - nval(occ, sdfg, q0, q1, zm);
      float ny = nval(occ, sdfg, q0, yp, q2) - nval(occ, sdfg, q0, ym, q2);
      float nz = nval(occ, sdfg, xp, q1, q2) - nval(occ, sdfg, xm, q1, q2);
      if (!interior) { nx = 0.f; ny = 0.f; nz = 0.f; }
      float r0 = vm[0]*nx + vm[1]*ny + vm[2]*nz;
      float r1 = vm[4]*nx + vm[5]*ny + vm[6]*nz;
      float r2 = vm[8]*nx + vm[9]*ny + vm[10]*nz;
      float nn = sqrtf(r0*r0 + r1*r1 + r2*r2);
      float inv = -1.0f / fmaxf(nn, EPSN);
      n0 = r0*inv; n1 = r1*inv; n2 = r2*inv;
    }
  }
  if (zsel == 0) {
    out_depths[(size_t)view*HW + p] = depth;
    float* on = out_norm + (size_t)view*HW*3;
    on[p*3+0] = n0; on[p*3+1] = n1; on[p*3+2] = n2;
    hit0[view*HW + p] = hit ? 1 : 0;
  } else {
    float* ont = out_normt + (size_t)view*HW*3;
    ont[p*3+0] = n0; ont[p*3+1] = n1; ont[p*3+2] = n2;
    hit1[view*HW + p] = hit ? 1 : 0;
  }
}

__global__ void __launch_bounds__(256) k_red1(
    const uint8_t* __restrict__ hit0_all, const uint8_t* __restrict__ hit1_all,
    const float* __restrict__ dimg_all, const float* __restrict__ dt_all,
    float* __restrict__ out_dt, Scal* __restrict__ sc_all) {
  __shared__ float sminD[4], smaxD[4], sminT[4], smaxT[4];
  __shared__ unsigned scntM[4], scntN[4];
  int vv = blockIdx.z;
  const uint8_t* hit0 = hit0_all + (size_t)vv*HW;
  const uint8_t* hit1 = hit1_all + (size_t)vv*HW;
  const float* dimg = dimg_all + (size_t)vv*HW;
  const float* dt = dt_all + (size_t)vv*HW;
  float* odt = out_dt + (size_t)vv*HW;
  Scal* sc = sc_all + vv;
  float lminD = 1e9f, lmaxD = 0.f, lminT = 1e9f, lmaxT = 0.f;
  unsigned lcntM = 0, lcntN = 0;
  for (int p = blockIdx.x * blockDim.x + threadIdx.x; p < HW;
       p += gridDim.x * blockDim.x) {
    bool h = hit0[p] != 0;
    float dtv = dt[p];
    odt[p] = dtv;  // fused passthrough copy
    if (h && dtv != 0.f) {
      float dv = dimg[p];
      lminD = fminf(lminD, dv); lmaxD = fmaxf(lmaxD, dv);
      lminT = fminf(lminT, dtv); lmaxT = fmaxf(lmaxT, dtv);
      lcntM++;
    }
    if (h && hit1[p] != 0) lcntN++;
  }
  for (int off = 32; off > 0; off >>= 1) {
    lminD = fminf(lminD, __shfl_down(lminD, off));
    lmaxD = fmaxf(lmaxD, __shfl_down(lmaxD, off));
    lminT = fminf(lminT, __shfl_down(lminT, off));
    lmaxT = fmaxf(lmaxT, __shfl_down(lmaxT, off));
    lcntM += __shfl_down(lcntM, off);
    lcntN += __shfl_down(lcntN, off);
  }
  int wid = threadIdx.x >> 6;
  if ((threadIdx.x & 63) == 0) {
    sminD[wid] = lminD; smaxD[wid] = lmaxD;
    sminT[wid] = lminT; smaxT[wid] = lmaxT;
    scntM[wid] = lcntM; scntN[wid] = lcntN;
  }
  __syncthreads();
  if (threadIdx.x == 0) {
    float mnD = sminD[0], mxD = smaxD[0], mnT = sminT[0], mxT = smaxT[0];
    unsigned cM = scntM[0], cN = scntN[0];
    for (int w = 1; w < 4; ++w) {
      mnD = fminf(mnD, sminD[w]); mxD = fmaxf(mxD, smaxD[w]);
      mnT = fminf(mnT, sminT[w]); mxT = fmaxf(mxT, smaxT[w]);
      cM += scntM[w]; cN += scntN[w];
    }
    atomicMin(&sc->minD, __float_as_uint(mnD));
    atomicMax(&sc->maxD, __float_as_uint(mxD));
    atomicMin(&sc->minT, __float_as_uint(mnT));
    atomicMax(&sc->maxT, __float_as_uint(mxT));
    if (cM) atomicAdd(&sc->cntM, cM);
    if (cN) atomicAdd(&sc->cntN, cN);
  }
}

__global__ void __launch_bounds__(256) k_red2(
    const uint8_t* __restrict__ hit0_all, const uint8_t* __restrict__ hit1_all,
    const float* __restrict__ dimg_all, const float* __restrict__ dt_all,
    const float* __restrict__ nimg_all, const float* __restrict__ ntimg_all,
    Scal* __restrict__ sc_all) {
  __shared__ float ssD[4], ssN[4];
  int vv = blockIdx.z;
  const uint8_t* hit0 = hit0_all + (size_t)vv*HW;
  const uint8_t* hit1 = hit1_all + (size_t)vv*HW;
  const float* dimg = dimg_all + (size_t)vv*HW;
  const float* dt = dt_all + (size_t)vv*HW;
  const float* nimg = nimg_all + (size_t)vv*HW*3;
  const float* ntimg = ntimg_all + (size_t)vv*HW*3;
  Scal* sc = sc_all + vv;
  float vminD = __uint_as_float(sc->minD);
  float vmaxD = __uint_as_float(sc->maxD) - vminD;
  float denD = (vmaxD <= 0.f) ? 1.f : vmaxD;
  float vminT = __uint_as_float(sc->minT);
  float vmaxT = __uint_as_float(sc->maxT) - vminT;
  float denT = (vmaxT <= 0.f) ? 1.f : vmaxT;
  float sD = 0.f, sN = 0.f;
  for (int p = blockIdx.x * blockDim.x + threadIdx.x; p < HW;
       p += gridDim.x * blockDim.x) {
    bool h = hit0[p] != 0;
    float dtv = dt[p];
    if (h && dtv != 0.f) {
      sD += fabsf((dimg[p] - vminD) / denD - (dtv - vminT) / denT);
    }
    if (h && hit1[p] != 0) {
      sN += fabsf(nimg[p*3+0] - ntimg[p*3+0])
          + fabsf(nimg[p*3+1] - ntimg[p*3+1])
          + fabsf(nimg[p*3+2] - ntimg[p*3+2]);
    }
  }
  for (int off = 32; off > 0; off >>= 1) {
    sD += __shfl_down(sD, off);
    sN += __shfl_down(sN, off);
  }
  int wid = threadIdx.x >> 6;
  if ((threadIdx.x & 63) == 0) { ssD[wid] = sD; ssN[wid] = sN; }
  __syncthreads();
  if (threadIdx.x == 0) {
    float tD = ssD[0] + ssD[1] + ssD[2] + ssD[3];
    float tN = ssN[0] + ssN[1] + ssN[2] + ssN[3];
    if (tD != 0.f) atomicAdd(&sc->sumD, tD);
    if (tN != 0.f) atomicAdd(&sc->sumN, tN);
  }
}

__global__ void k_write_loss(const Scal* __restrict__ sc, float* __restrict__ out) {
  float lossD = 0.f, lossN = 0.f;
  for (int v = 0; v < 2; ++v) {
    float ld = (sc[v].cntM > 0) ? sc[v].sumD / (float)sc[v].cntM : 0.f;
    float ln = (sc[v].cntN > 0) ? sc[v].sumN / (float)(3u * sc[v].cntN) : 0.f;
    lossD += ld * 0.5f;  // WEIGHT / N_VIEWS
    lossN += ln * 0.5f;
  }
  out[0] = lossD;
  out[1] = lossN;
}

extern "C" void kernel_launch(void* const* d_in, const int* in_sizes, int n_in,
                              void* d_out, int out_size, void* d_ws, size_t ws_size,
                              hipStream_t stream) {
  const int*   coords = (const int*)d_in[0];
  const float* origin = (const float*)d_in[1];
  const float* sdf    = (const float*)d_in[2];
  const float* sdft   = (const float*)d_in[3];
  const float* dt     = (const float*)d_in[4];
  const float* intr   = (const float*)d_in[5];
  const float* viewm  = (const float*)d_in[6];
  float* out = (float*)d_out;

  char* w = (char*)d_ws;
  float* g        = (float*)w;                       // D3 f32
  float* gt       = g + D3;                          // D3 f32
  uint32_t* coarse = (uint32_t*)(gt + D3);           // 512 u32 (8^3 padded)
  Scal* sc        = (Scal*)(coarse + 512);           // 2 structs
  uint8_t* occ    = (uint8_t*)(sc + 2);              // D3 bytes
  uint8_t* cellok = occ + D3;                        // D3 bytes
  uint8_t* hit0   = cellok + D3;                     // 2*HW bytes
  uint8_t* hit1   = hit0 + 2*(size_t)HW;             // 2*HW bytes

  float* out_depths = out + 2;                 // 2*HW
  float* out_dt     = out + 2 + 2*(size_t)HW;  // 2*HW
  float* out_norm   = out + 2 + 4*(size_t)HW;  // 2*HW*3
  float* out_normt  = out + 2 + 10*(size_t)HW; // 2*HW*3

  k_init<<<(D3+255)/256, 256, 0, stream>>>(g, gt, occ, coarse, sc);
  k_scatter<<<(NPTS+255)/256, 256, 0, stream>>>(coords, sdf, sdft, g, gt, occ);
  k_cellok<<<(D3+255)/256, 256, 0, stream>>>(occ, cellok, coarse);
  k_raycast<<<dim3((HW+255)/256, 1, 4), 256, 0, stream>>>(
      g, gt, occ, cellok, coarse, viewm, intr, origin,
      out_depths, out_norm, out_normt, hit0, hit1);
  k_red1<<<dim3(RED_BLOCKS, 1, 2), 256, 0, stream>>>(hit0, hit1, out_depths, dt, out_dt, sc);
  k_red2<<<dim3(RED_BLOCKS, 1, 2), 256, 0, stream>>>(hit0, hit1, out_depths, dt,
                                                     out_norm, out_normt, sc);
  k_write_loss<<<1, 1, 0, stream>>>(sc, out);
}

// Round 4
// 134.562 us; speedup vs baseline: 5.0535x; 1.2278x over previous
//
#include <hip/hip_runtime.h>
#include <stdint.h>

#define D 96
#define D2 (96*96)
#define D3 (96*96*96)
#define IMW 640
#define IMH 480
#define HW (IMW*IMH)
#define NPTS 150000
#define VOXEL 0.04f
#define TRUNC 5.0f
#define RAYINC 1.5f
#define DEPTHMIN 0.025f
#define NSTEPS 67
#define EPSN 1e-5f
#define RED_BLOCKS 240
#define RAY_BLOCKS 480

struct Scal {
  unsigned minD, maxD, minT, maxT, cntM, cntN;
  float sumD, sumN;
};

// ws layout: coarse(512 u32) | aabb(6 int) | done(1 u32) | sc(2) | g(D3 f32) | gt(D3 f32)
//            | occ(D3 u8) | cellok(D3 u8) | hit0(2HW u8) | hit1(2HW u8)

__global__ void k_init(uint8_t* __restrict__ occ, uint32_t* __restrict__ coarse,
                       int* __restrict__ aabb, unsigned* __restrict__ done,
                       Scal* __restrict__ sc) {
  int i = blockIdx.x * blockDim.x + threadIdx.x;
  if (i < D3) occ[i] = 0;
  if (i < 512) coarse[i] = 0u;
  if (i < 3) aabb[i] = 0x7fffffff;       // mn
  else if (i < 6) aabb[i] = -1;          // mx
  if (i == 6) *done = 0u;
  if (i < 2) {
    sc[i].minD = __float_as_uint(1e9f);
    sc[i].maxD = 0u;
    sc[i].minT = __float_as_uint(1e9f);
    sc[i].maxT = 0u;
    sc[i].cntM = 0u; sc[i].cntN = 0u;
    sc[i].sumD = 0.f; sc[i].sumN = 0.f;
  }
}

__global__ void k_scatter(const int* __restrict__ coords, const float* __restrict__ sdf,
                          const float* __restrict__ sdft,
                          float* __restrict__ g, float* __restrict__ gt,
                          uint8_t* __restrict__ occ) {
  int i = blockIdx.x * blockDim.x + threadIdx.x;
  if (i >= NPTS) return;
  int l0 = coords[i*4+3], l1 = coords[i*4+2], l2 = coords[i*4+1];
  int id = (l0*D + l1)*D + l2;
  g[id] = sdf[i];
  gt[id] = sdft[i];
  occ[id] = 1;
}

__global__ void k_cellok(const uint8_t* __restrict__ occ, uint8_t* __restrict__ cellok,
                         uint32_t* __restrict__ coarse, int* __restrict__ aabb) {
  int i = blockIdx.x * blockDim.x + threadIdx.x;
  if (i >= D3) return;
  int c2 = i % D, c1 = (i / D) % D, c0 = i / D2;
  uint8_t ok = 0;
  if (c0 <= D-2 && c1 <= D-2 && c2 <= D-2) {
    ok = occ[i] & occ[i+1] & occ[i+D] & occ[i+D+1]
       & occ[i+D2] & occ[i+D2+1] & occ[i+D2+D] & occ[i+D2+D+1];
  }
  cellok[i] = ok;
  if (ok) {
    int w = ((c0>>4)+1)*64 + ((c1>>4)+1)*8 + ((c2>>4)+1);
    atomicOr(&coarse[w], 1u);
    atomicMin(&aabb[0], c0); atomicMin(&aabb[1], c1); atomicMin(&aabb[2], c2);
    atomicMax(&aabb[3], c0); atomicMax(&aabb[4], c1); atomicMax(&aabb[5], c2);
  }
}

__device__ __forceinline__ float nval(const uint8_t* occ, const float* gr, int a, int b, int c) {
  int id = (a*D + b)*D + c;
  return occ[id] ? gr[id] : 0.0f;
}

__device__ __forceinline__ void comp_normal(const uint8_t* __restrict__ occ,
                                            const float* __restrict__ sdfg,
                                            const float* __restrict__ vm,
                                            int q0, int q1, int q2,
                                            float& n0, float& n1, float& n2) {
  int qid = (q0*D + q1)*D + q2;
  if (!occ[qid]) return;
  bool interior = (q0>=1) & (q0<D-1) & (q1>=1) & (q1<D-1) & (q2>=1) & (q2<D-1);
  int zp = min(q2+1, D-1), zm = max(q2-1, 0);
  int yp = min(q1+1, D-1), ym = max(q1-1, 0);
  int xp = min(q0+1, D-1), xm = max(q0-1, 0);
  float nx = nval(occ, sdfg, q0, q1, zp) - nval(occ, sdfg, q0, q1, zm);
  float ny = nval(occ, sdfg, q0, yp, q2) - nval(occ, sdfg, q0, ym, q2);
  float nz = nval(occ, sdfg, xp, q1, q2) - nval(occ, sdfg, xm, q1, q2);
  if (!interior) { nx = 0.f; ny = 0.f; nz = 0.f; }
  float r0 = vm[0]*nx + vm[1]*ny + vm[2]*nz;
  float r1 = vm[4]*nx + vm[5]*ny + vm[6]*nz;
  float r2 = vm[8]*nx + vm[9]*ny + vm[10]*nz;
  float nn = sqrtf(r0*r0 + r1*r1 + r2*r2);
  float inv = -1.0f / fmaxf(nn, EPSN);
  n0 = r0*inv; n1 = r1*inv; n2 = r2*inv;
}

__global__ void __launch_bounds__(256) k_raycast(
    const float* __restrict__ g, const float* __restrict__ gt,
    const uint8_t* __restrict__ occ, const uint8_t* __restrict__ cellok,
    const uint32_t* __restrict__ coarse, const int* __restrict__ aabb,
    const float* __restrict__ viewm_all, const float* __restrict__ intr_all,
    const float* __restrict__ origin, const float* __restrict__ dt_all,
    float* __restrict__ out_depths, float* __restrict__ out_dt,
    float* __restrict__ out_norm, float* __restrict__ out_normt,
    uint8_t* __restrict__ hit0, uint8_t* __restrict__ hit1,
    Scal* __restrict__ sc_all) {
  __shared__ float sminD[4], smaxD[4], sminT[4], smaxT[4];
  __shared__ unsigned scntM[4], scntN[4];
  int view = blockIdx.z;
  const float* vm = viewm_all + view*16;
  const float* km = intr_all + view*16;
  const float* dtp = dt_all + (size_t)view*HW;
  float* odp = out_depths + (size_t)view*HW;
  float* odt = out_dt + (size_t)view*HW;
  float* on  = out_norm + (size_t)view*HW*3;
  float* ont = out_normt + (size_t)view*HW*3;
  uint8_t* h0 = hit0 + (size_t)view*HW;
  uint8_t* h1 = hit1 + (size_t)view*HW;

  // camera (uniform across threads)
  float fx = km[0], fy = km[5], cx = km[2], cy = km[6];
  float tc0 = -(vm[0]*vm[3] + vm[4]*vm[7] + vm[8]*vm[11]);
  float tc1 = -(vm[1]*vm[3] + vm[5]*vm[7] + vm[9]*vm[11]);
  float tc2 = -(vm[2]*vm[3] + vm[6]*vm[7] + vm[10]*vm[11]);
  float cam0 = (tc0 - origin[0]) / VOXEL;
  float cam1 = (tc1 - origin[1]) / VOXEL;
  float cam2 = (tc2 - origin[2]) / VOXEL;
  // AABB of cellok-true cells
  int mn0 = aabb[0], mn1 = aabb[1], mn2 = aabb[2];
  int mx0 = aabb[3], mx1 = aabb[4], mx2 = aabb[5];
  bool any_cell = (mn0 <= mx0);
  float lo0 = (float)mn0, hi0 = (float)(mx0+1);
  float lo1 = (float)mn1, hi1 = (float)(mx1+1);
  float lo2 = (float)mn2, hi2 = (float)(mx2+1);

  // red1 local accumulators
  float lminD = 1e9f, lmaxD = 0.f, lminT = 1e9f, lmaxT = 0.f;
  unsigned lcntM = 0, lcntN = 0;

  for (int p = blockIdx.x * blockDim.x + threadIdx.x; p < HW;
       p += gridDim.x * blockDim.x) {
    float u = (float)(p % IMW), v = (float)(p / IMW);
    float dc0 = (u - cx) / fx, dc1 = (v - cy) / fy, dc2 = 1.0f;
    float dw0 = vm[0]*dc0 + vm[4]*dc1 + vm[8]*dc2;
    float dw1 = vm[1]*dc0 + vm[5]*dc1 + vm[9]*dc2;
    float dw2 = vm[2]*dc0 + vm[6]*dc1 + vm[10]*dc2;
    float nrm = sqrtf(dw0*dw0 + dw1*dw1 + dw2*dw2);
    dw0 /= nrm; dw1 /= nrm; dw2 /= nrm;

    // slab clamp against cellok AABB
    float tmin = DEPTHMIN, tmax = DEPTHMIN + RAYINC * (float)(NSTEPS - 1);
    if (!any_cell) { tmin = 1e30f; tmax = -1e30f; }
    else {
      float cams[3] = {cam0, cam1, cam2};
      float dws[3]  = {dw0, dw1, dw2};
      float los[3]  = {lo0, lo1, lo2};
      float his[3]  = {hi0, hi1, hi2};
      #pragma unroll
      for (int a = 0; a < 3; ++a) {
        float dwa = dws[a], cama = cams[a];
        if (fabsf(dwa) < 1e-8f) {
          if (cama < los[a] || cama > his[a]) { tmin = 1e30f; tmax = -1e30f; }
        } else {
          float inv = 1.0f / dwa;
          float t0 = (los[a] - cama) * inv, t1 = (his[a] - cama) * inv;
          tmin = fmaxf(tmin, fminf(t0, t1));
          tmax = fminf(tmax, fmaxf(t0, t1));
        }
      }
    }
    int st_lo = NSTEPS, st_hi = 0;
    if (tmax >= tmin) {
      st_lo = max((int)ceilf((tmin - DEPTHMIN) / RAYINC) - 1, 0);
      st_hi = min((int)floorf((tmax - DEPTHMIN) / RAYINC) + 2, NSTEPS);
    }

    bool hitg = false, hitt = false;
    float thg = 0.f, tht = 0.f;
    float prev_s = 0.f, prev_st = 0.f;
    int last_ok = -5;
    for (int st = st_lo; st < st_hi; ++st) {
      float t = DEPTHMIN + RAYINC * (float)st;
      float p0f = cam0 + t*dw0, p1f = cam1 + t*dw1, p2f = cam2 + t*dw2;
      int c0 = (int)floorf(p0f), c1 = (int)floorf(p1f), c2 = (int)floorf(p2f);
      if (c0 >= 0 && c0 <= D-2 && c1 >= 0 && c1 <= D-2 && c2 >= 0 && c2 <= D-2) {
        int widx = ((c0 >> 4) << 6) + ((c1 >> 4) << 3) + (c2 >> 4) + 73;
        if (coarse[widx]) {
          int base = (c0*D + c1)*D + c2;
          if (cellok[base]) {
            float a0 = p0f - (float)c0, a1 = p1f - (float)c1, a2 = p2f - (float)c2;
            float b0 = 1.f - a0, b1 = 1.f - a1, b2 = 1.f - a2;
            float w000 = b0*b1*b2, w001 = b0*b1*a2, w010 = b0*a1*b2, w011 = b0*a1*a2;
            float w100 = a0*b1*b2, w101 = a0*b1*a2, w110 = a0*a1*b2, w111 = a0*a1*a2;
            float s = w000*g[base] + w001*g[base+1] + w010*g[base+D] + w011*g[base+D+1]
                    + w100*g[base+D2] + w101*g[base+D2+1]
                    + w110*g[base+D2+D] + w111*g[base+D2+D+1];
            float sv = w000*gt[base] + w001*gt[base+1] + w010*gt[base+D] + w011*gt[base+D+1]
                     + w100*gt[base+D2] + w101*gt[base+D2+1]
                     + w110*gt[base+D2+D] + w111*gt[base+D2+D+1];
            if (last_ok == st-1) {
              if (prev_s > 0.f && s <= 0.f && !hitg) {
                float denom = prev_s - s;
                if (fabsf(denom) < 1e-8f) denom = 1e-8f;
                thg = t - RAYINC + RAYINC * (prev_s / denom);
                hitg = true;
              }
              if (prev_st > 0.f && sv <= 0.f && !hitt) {
                float denom = prev_st - sv;
                if (fabsf(denom) < 1e-8f) denom = 1e-8f;
                tht = t - RAYINC + RAYINC * (prev_st / denom);
                hitt = true;
              }
            }
            last_ok = st;
            prev_s = s;
            prev_st = sv;
          }
        }
      }
    }

    float depth = hitg ? thg * VOXEL : 0.0f;
    float n0 = 0.f, n1 = 0.f, n2 = 0.f;
    float m0 = 0.f, m1 = 0.f, m2 = 0.f;
    if (hitg) {
      float ph0 = cam0 + thg*dw0, ph1 = cam1 + thg*dw1, ph2 = cam2 + thg*dw2;
      int q0 = min(max((int)rintf(ph0), 0), D-1);
      int q1 = min(max((int)rintf(ph1), 0), D-1);
      int q2 = min(max((int)rintf(ph2), 0), D-1);
      comp_normal(occ, g, vm, q0, q1, q2, n0, n1, n2);
    }
    if (hitt) {
      float ph0 = cam0 + tht*dw0, ph1 = cam1 + tht*dw1, ph2 = cam2 + tht*dw2;
      int q0 = min(max((int)rintf(ph0), 0), D-1);
      int q1 = min(max((int)rintf(ph1), 0), D-1);
      int q2 = min(max((int)rintf(ph2), 0), D-1);
      comp_normal(occ, gt, vm, q0, q1, q2, m0, m1, m2);
    }
    float dtv = dtp[p];
    odp[p] = depth;
    odt[p] = dtv;
    on[p*3+0] = n0;  on[p*3+1] = n1;  on[p*3+2] = n2;
    ont[p*3+0] = m0; ont[p*3+1] = m1; ont[p*3+2] = m2;
    h0[p] = hitg ? 1 : 0;
    h1[p] = hitt ? 1 : 0;

    if (hitg && dtv != 0.f) {
      lminD = fminf(lminD, depth); lmaxD = fmaxf(lmaxD, depth);
      lminT = fminf(lminT, dtv);   lmaxT = fmaxf(lmaxT, dtv);
      lcntM++;
    }
    if (hitg && hitt) lcntN++;
  }

  // block reduce red1 quantities, one atomic set per block
  for (int off = 32; off > 0; off >>= 1) {
    lminD = fminf(lminD, __shfl_down(lminD, off));
    lmaxD = fmaxf(lmaxD, __shfl_down(lmaxD, off));
    lminT = fminf(lminT, __shfl_down(lminT, off));
    lmaxT = fmaxf(lmaxT, __shfl_down(lmaxT, off));
    lcntM += __shfl_down(lcntM, off);
    lcntN += __shfl_down(lcntN, off);
  }
  int wid = threadIdx.x >> 6;
  if ((threadIdx.x & 63) == 0) {
    sminD[wid] = lminD; smaxD[wid] = lmaxD;
    sminT[wid] = lminT; smaxT[wid] = lmaxT;
    scntM[wid] = lcntM; scntN[wid] = lcntN;
  }
  __syncthreads();
  if (threadIdx.x == 0) {
    Scal* sc = sc_all + view;
    float mnD = sminD[0], mxD = smaxD[0], mnT = sminT[0], mxT = smaxT[0];
    unsigned cM = scntM[0], cN = scntN[0];
    for (int w2 = 1; w2 < 4; ++w2) {
      mnD = fminf(mnD, sminD[w2]); mxD = fmaxf(mxD, smaxD[w2]);
      mnT = fminf(mnT, sminT[w2]); mxT = fmaxf(mxT, smaxT[w2]);
      cM += scntM[w2]; cN += scntN[w2];
    }
    atomicMin(&sc->minD, __float_as_uint(mnD));
    atomicMax(&sc->maxD, __float_as_uint(mxD));
    atomicMin(&sc->minT, __float_as_uint(mnT));
    atomicMax(&sc->maxT, __float_as_uint(mxT));
    if (cM) atomicAdd(&sc->cntM, cM);
    if (cN) atomicAdd(&sc->cntN, cN);
  }
}

__global__ void __launch_bounds__(256) k_red2(
    const uint8_t* __restrict__ hit0_all, const uint8_t* __restrict__ hit1_all,
    const float* __restrict__ dimg_all, const float* __restrict__ dt_all,
    const float* __restrict__ nimg_all, const float* __restrict__ ntimg_all,
    Scal* __restrict__ sc_all, unsigned* __restrict__ done,
    float* __restrict__ out) {
  __shared__ float ssD[4], ssN[4];
  int vv = blockIdx.z;
  const uint8_t* hit0 = hit0_all + (size_t)vv*HW;
  const uint8_t* hit1 = hit1_all + (size_t)vv*HW;
  const float* dimg = dimg_all + (size_t)vv*HW;
  const float* dt = dt_all + (size_t)vv*HW;
  const float* nimg = nimg_all + (size_t)vv*HW*3;
  const float* ntimg = ntimg_all + (size_t)vv*HW*3;
  Scal* sc = sc_all + vv;
  float vminD = __uint_as_float(sc->minD);
  float vmaxD = __uint_as_float(sc->maxD) - vminD;
  float denD = (vmaxD <= 0.f) ? 1.f : vmaxD;
  float vminT = __uint_as_float(sc->minT);
  float vmaxT = __uint_as_float(sc->maxT) - vminT;
  float denT = (vmaxT <= 0.f) ? 1.f : vmaxT;
  float sD = 0.f, sN = 0.f;
  for (int p = blockIdx.x * blockDim.x + threadIdx.x; p < HW;
       p += gridDim.x * blockDim.x) {
    bool h = hit0[p] != 0;
    float dtv = dt[p];
    if (h && dtv != 0.f) {
      sD += fabsf((dimg[p] - vminD) / denD - (dtv - vminT) / denT);
    }
    if (h && hit1[p] != 0) {
      sN += fabsf(nimg[p*3+0] - ntimg[p*3+0])
          + fabsf(nimg[p*3+1] - ntimg[p*3+1])
          + fabsf(nimg[p*3+2] - ntimg[p*3+2]);
    }
  }
  for (int off = 32; off > 0; off >>= 1) {
    sD += __shfl_down(sD, off);
    sN += __shfl_down(sN, off);
  }
  int wid = threadIdx.x >> 6;
  if ((threadIdx.x & 63) == 0) { ssD[wid] = sD; ssN[wid] = sN; }
  __syncthreads();
  if (threadIdx.x == 0) {
    float tD = ssD[0] + ssD[1] + ssD[2] + ssD[3];
    float tN = ssN[0] + ssN[1] + ssN[2] + ssN[3];
    if (tD != 0.f) atomicAdd(&sc->sumD, tD);
    if (tN != 0.f) atomicAdd(&sc->sumN, tN);
    __threadfence();
    unsigned prev = atomicAdd(done, 1u);
    if (prev == (unsigned)(2 * RED_BLOCKS - 1)) {
      // all blocks' sums visible (threadfence-before-add + atomic ordering)
      __threadfence();
      float lossD = 0.f, lossN = 0.f;
      for (int v = 0; v < 2; ++v) {
        unsigned cM = __hip_atomic_load(&sc_all[v].cntM, __ATOMIC_ACQUIRE, __HIP_MEMORY_SCOPE_AGENT);
        unsigned cN = __hip_atomic_load(&sc_all[v].cntN, __ATOMIC_ACQUIRE, __HIP_MEMORY_SCOPE_AGENT);
        float suD = __hip_atomic_load(&sc_all[v].sumD, __ATOMIC_ACQUIRE, __HIP_MEMORY_SCOPE_AGENT);
        float suN = __hip_atomic_load(&sc_all[v].sumN, __ATOMIC_ACQUIRE, __HIP_MEMORY_SCOPE_AGENT);
        float ld = (cM > 0) ? suD / (float)cM : 0.f;
        float ln = (cN > 0) ? suN / (float)(3u * cN) : 0.f;
        lossD += ld * 0.5f;  // WEIGHT / N_VIEWS
        lossN += ln * 0.5f;
      }
      out[0] = lossD;
      out[1] = lossN;
    }
  }
}

extern "C" void kernel_launch(void* const* d_in, const int* in_sizes, int n_in,
                              void* d_out, int out_size, void* d_ws, size_t ws_size,
                              hipStream_t stream) {
  const int*   coords = (const int*)d_in[0];
  const float* origin = (const float*)d_in[1];
  const float* sdf    = (const float*)d_in[2];
  const float* sdft   = (const float*)d_in[3];
  const float* dt     = (const float*)d_in[4];
  const float* intr   = (const float*)d_in[5];
  const float* viewm  = (const float*)d_in[6];
  float* out = (float*)d_out;

  char* w = (char*)d_ws;
  uint32_t* coarse = (uint32_t*)w;                   // 512 u32
  int* aabb       = (int*)(coarse + 512);            // 6 int
  unsigned* done  = (unsigned*)(aabb + 6);           // 1 u32
  Scal* sc        = (Scal*)(done + 1);               // 2 structs
  float* g        = (float*)(sc + 2);                // D3 f32 (no background fill needed)
  float* gt       = g + D3;                          // D3 f32
  uint8_t* occ    = (uint8_t*)(gt + D3);             // D3 u8
  uint8_t* cellok = occ + D3;                        // D3 u8
  uint8_t* hit0   = cellok + D3;                     // 2*HW u8
  uint8_t* hit1   = hit0 + 2*(size_t)HW;             // 2*HW u8

  float* out_depths = out + 2;                 // 2*HW
  float* out_dt     = out + 2 + 2*(size_t)HW;  // 2*HW
  float* out_norm   = out + 2 + 4*(size_t)HW;  // 2*HW*3
  float* out_normt  = out + 2 + 10*(size_t)HW; // 2*HW*3

  k_init<<<(D3+255)/256, 256, 0, stream>>>(occ, coarse, aabb, done, sc);
  k_scatter<<<(NPTS+255)/256, 256, 0, stream>>>(coords, sdf, sdft, g, gt, occ);
  k_cellok<<<(D3+255)/256, 256, 0, stream>>>(occ, cellok, coarse, aabb);
  k_raycast<<<dim3(RAY_BLOCKS, 1, 2), 256, 0, stream>>>(
      g, gt, occ, cellok, coarse, aabb, viewm, intr, origin, dt,
      out_depths, out_dt, out_norm, out_normt, hit0, hit1, sc);
  k_red2<<<dim3(RED_BLOCKS, 1, 2), 256, 0, stream>>>(
      hit0, hit1, out_depths, dt, out_norm, out_normt, sc, done, out);
}